// Round 11
// baseline (1449.539 us; speedup 1.0000x reference)
//
#include <hip/hip_runtime.h>
#include <cstddef>

#define Bz 32
#define Lz 1024
#define Hz 256
#define Nz (Bz*Lz)          // 32768
#define NHz ((size_t)Nz*Hz) // 8388608
#define BHz (Bz*Hz)         // 8192
#define EPSz 1e-3f
#define NLAYERS 4
#define NCH 64              // 16-row softmax chunks per batch
#define NTC 112             // tile-cols in pre (7 gates * 16)
#define CHR 16384           // rows per GEMM/epi chunk

typedef __bf16 bf8_t __attribute__((ext_vector_type(8)));
typedef __bf16 bf4_t __attribute__((ext_vector_type(4)));
typedef float  f4_t  __attribute__((ext_vector_type(4)));

__device__ inline float sigmoidf(float x){ return 1.f/(1.f+expf(-x)); }
// fast versions (v_exp_f32 / v_rcp_f32): rel err ~1e-7, invisible under bf16 rounding
__device__ inline float fsig(float x){ return __builtin_amdgcn_rcpf(1.f + __expf(-x)); }
__device__ inline float ftanh(float x){ return 1.f - 2.f*__builtin_amdgcn_rcpf(__expf(2.f*x)+1.f); }

// DPP row_shr add: reduce over the 16-lane DPP row on the VALU pipe (not DS).
// After shr 1,2,4,8 lane (lane&15)==15 holds the 16-lane row sum.
template<int C>
__device__ inline float dppadd(float v){
  int t = __builtin_amdgcn_update_dpp(0, __builtin_bit_cast(int, v), C, 0xf, 0xf, true);
  return v + __builtin_bit_cast(float, t);
}
__device__ inline float dppsum16(float v){
  v = dppadd<0x111>(v);   // row_shr:1
  v = dppadd<0x112>(v);   // row_shr:2
  v = dppadd<0x114>(v);   // row_shr:4
  v = dppadd<0x118>(v);   // row_shr:8
  return v;
}

// async global->LDS, 16B per lane.  LDS dest must be uniform-base + lane*16.
__device__ inline void gl_lds16(const void* g, void* l){
  __builtin_amdgcn_global_load_lds(
      (const __attribute__((address_space(1))) void*)g,
      (__attribute__((address_space(3))) void*)l, 16, 0, 0);
}

__device__ inline float2 block_sum2(float a, float b, float* red){
  #pragma unroll
  for (int off=32; off; off>>=1){ a += __shfl_down(a,off,64); b += __shfl_down(b,off,64); }
  int w = threadIdx.x>>6;
  __syncthreads();
  if ((threadIdx.x&63)==0){ red[w]=a; red[4+w]=b; }
  __syncthreads();
  return make_float2(red[0]+red[1]+red[2]+red[3], red[4]+red[5]+red[6]+red[7]);
}

__device__ inline float ln_block(float v, const float* la, const float* lb, int t, float* red){
  float2 ss = block_sum2(v, v*v, red);
  float mean = ss.x*(1.f/Hz);
  float var  = (ss.y - (float)Hz*mean*mean)*(1.f/(Hz-1));
  float isd  = 1.f/(sqrtf(fmaxf(var,0.f))+EPSz);
  return la[t]*(v-mean)*isd + lb[t];
}

// ---- init: xe = word*mask, h = h0*mask, c = c0*mask (all bf16) ----
__global__ void k_initb(const float* __restrict__ word, const float* __restrict__ h0,
                        const float* __restrict__ c0, const float* __restrict__ mask,
                        __bf16* __restrict__ xe, __bf16* __restrict__ h, __bf16* __restrict__ c){
  int tid = blockIdx.x*256 + threadIdx.x;      // Nz*32 threads
  int n = tid >> 5; int c8 = (tid & 31)*8;
  float m = mask[n];
  size_t off = (size_t)n*Hz + c8;
  const float4* wv = (const float4*)(word + off);
  float4 w0 = wv[0], w1 = wv[1];
  bf8_t o;
  o[0]=(__bf16)(w0.x*m); o[1]=(__bf16)(w0.y*m); o[2]=(__bf16)(w0.z*m); o[3]=(__bf16)(w0.w*m);
  o[4]=(__bf16)(w1.x*m); o[5]=(__bf16)(w1.y*m); o[6]=(__bf16)(w1.z*m); o[7]=(__bf16)(w1.w*m);
  *(bf8_t*)(xe + off) = o;
  const float4* hv = (const float4*)(h0 + off);
  float4 a0 = hv[0], a1 = hv[1];
  o[0]=(__bf16)(a0.x*m); o[1]=(__bf16)(a0.y*m); o[2]=(__bf16)(a0.z*m); o[3]=(__bf16)(a0.w*m);
  o[4]=(__bf16)(a1.x*m); o[5]=(__bf16)(a1.y*m); o[6]=(__bf16)(a1.z*m); o[7]=(__bf16)(a1.w*m);
  *(bf8_t*)(h + off) = o;
  const float4* cv = (const float4*)(c0 + off);
  float4 b0 = cv[0], b1 = cv[1];
  o[0]=(__bf16)(b0.x*m); o[1]=(__bf16)(b0.y*m); o[2]=(__bf16)(b0.z*m); o[3]=(__bf16)(b0.w*m);
  o[4]=(__bf16)(b1.x*m); o[5]=(__bf16)(b1.y*m); o[6]=(__bf16)(b1.z*m); o[7]=(__bf16)(b1.w*m);
  *(bf8_t*)(c + off) = o;
}

// ---- pack 7-gate weights into Wt[col][k] row-major (1792 x 1024, bf16) ----
__global__ void k_packWt(const float* __restrict__ Wx, const float* __restrict__ Wh,
                         const float* __restrict__ Wi, const float* __restrict__ gWh3,
                         __bf16* __restrict__ Wt, __bf16* __restrict__ zbuf){
  int tid = blockIdx.x*256 + threadIdx.x;   // 896*256 = 1792*128
  if (tid < 128) zbuf[tid] = (__bf16)0.f;
  int col = tid >> 7;
  int k0  = (tid & 127) << 3;
  if (col >= 1792) return;
  int g = col >> 8, cg = col & 255;
  int seg = k0 >> 8, kl0 = k0 & 255;        // 8 consecutive k stay in one seg
  bf8_t o;
  #pragma unroll
  for (int j=0;j<8;j++){
    int kl = kl0 + j;
    float v = 0.f;
    if (g < 6){
      if (seg==0)      v = Wx[((size_t)g*256 + kl)*256 + cg];
      else if (seg==1) v = Wh[((size_t)g*512 + kl)*256 + cg];
      else if (seg==2) v = Wh[((size_t)g*512 + 256 + kl)*256 + cg];
      else             v = Wi[((size_t)g*256 + kl)*256 + cg];
    } else {
      if (seg==3)      v = gWh3[(size_t)kl*256 + cg];
    }
    o[j] = (__bf16)v;
  }
  *(bf8_t*)(Wt + (size_t)col*1024 + k0) = o;
}

// ---- mean over L of a bf16 tensor, two-stage ----
__global__ void k_meanpb(const __bf16* __restrict__ x, float* __restrict__ part){
  int b = blockIdx.x, ch = blockIdx.y, t = threadIdx.x;
  const __bf16* p = x + ((size_t)b*Lz + ch*128)*Hz + t;
  float s = 0.f;
  #pragma unroll 4
  for (int l=0;l<128;l++) s += (float)p[(size_t)l*Hz];
  part[(b*8+ch)*Hz + t] = s;
}
__global__ void k_comb8(const float* __restrict__ part, float* __restrict__ o){
  int b = blockIdx.x, t = threadIdx.x;
  float s = 0.f;
  #pragma unroll
  for (int ch=0;ch<8;ch++) s += part[(b*8+ch)*Hz + t];
  o[b*Hz+t] = s*(1.f/Lz);
}

// ---- sentence-level gates + broadcast matvecs.  grid (B, 11) ----
__global__ __launch_bounds__(256) void k_small(
    const float* __restrict__ dh, const float* __restrict__ comb, const float* __restrict__ sent,
    const float* __restrict__ gWx, const float* __restrict__ gWh, const float* __restrict__ gWg,
    const float* __restrict__ gb, const float* __restrict__ Wd_g,
    const float* __restrict__ ln_a, const float* __restrict__ ln_b,
    float* __restrict__ gd, float* __restrict__ gi, float* __restrict__ go,
    float* __restrict__ tgg, float* __restrict__ dhWd7){
  int b = blockIdx.x, which = blockIdx.y, t = threadIdx.x;
  __shared__ float sdh[Hz], sse[Hz], sco[Hz];
  __shared__ float red[8];
  sdh[t]=dh[b*Hz+t]; sse[t]=sent[b*Hz+t]; sco[t]=comb[b*Hz+t];
  __syncthreads();
  float acc=0.f;
  if (which < 3){
    const float* W0 = gWx + which*Hz*Hz;
    const float* W1 = gWg + which*Hz*Hz;
    const float* W2 = gWh + which*Hz*Hz;
    for (int k=0;k<Hz;k++) acc += sdh[k]*W0[k*Hz+t] + sse[k]*W1[k*Hz+t] + sco[k]*W2[k*Hz+t];
    if (which==0){
      float r = ln_block(acc + gb[0*Hz+t], ln_a+6*Hz, ln_b+6*Hz, t, red);
      gd[b*Hz+t] = sigmoidf(r);
    } else if (which==1){
      float r = ln_block(acc, ln_a+9*Hz, ln_b+9*Hz, t, red);
      gi[b*Hz+t] = sigmoidf(r + gb[1*Hz+t]);
    } else {
      float r = ln_block(acc + gb[2*Hz+t], ln_a+7*Hz, ln_b+7*Hz, t, red);
      go[b*Hz+t] = sigmoidf(r);
    }
  } else if (which == 3){
    const float* W = gWg + 3*Hz*Hz;
    for (int k=0;k<Hz;k++) acc += sse[k]*W[k*Hz+t];
    float r = ln_block(acc, ln_a+10*Hz, ln_b+10*Hz, t, red);
    tgg[b*Hz+t] = tanhf(r);
  } else if (which == 4){
    const float* W = gWx + 3*Hz*Hz;          // dh @ gWx[3] -> slot 6
    for (int k=0;k<Hz;k++) acc += sdh[k]*W[k*Hz+t];
    dhWd7[(6*Bz + b)*Hz + t] = acc;
  } else {
    int g = which-5;
    const float* W = Wd_g + g*Hz*Hz;
    for (int k=0;k<Hz;k++) acc += sdh[k]*W[k*Hz+t];
    dhWd7[(g*Bz + b)*Hz + t] = acc;
  }
}

// ---- GEMM: [xe | h(n-1) | h(n+1) | h(n)](rows x 1024) @ Wt^T(1024 x 1792) -> pre ----
// v9 = round-4 best (128x128 tile, 4 waves, BK=64, double-buffered 2-phase)
// + XCD-aware block swizzle: the 14 gate-blocks sharing one bx (same 256KB
// A-panel) are grouped onto one XCD so A re-reads hit that XCD's L2.
__global__ __launch_bounds__(256) void k_gemm(
    const __bf16* __restrict__ xe, const __bf16* __restrict__ h,
    const __bf16* __restrict__ Wt, const __bf16* __restrict__ zbuf,
    __bf16* __restrict__ pre, int n_base){
  __shared__ __align__(16) __bf16 sA[2][128*64];   // [row][64] row-major, chunk-swizzled
  __shared__ __align__(16) __bf16 sB[2][128*64];   // [col][64] row-major, chunk-swizzled
  int t = threadIdx.x;
  int w = t>>6, lane = t&63;
  int m16 = lane&15, p = lane>>4;
  // XCD swizzle: flat hw id -> (bx, by) with by-major inside each XCD chunk.
  // 1792 blocks = 8 XCDs x 224; XCD r gets id2 in [224r, 224(r+1)) = bx in [16r,16r+16).
  int flat = blockIdx.y*128 + blockIdx.x;          // 0..1791
  int id2  = (flat&7)*224 + (flat>>3);             // bijective (1792 = 8*224)
  int bx = id2/14, by = id2%14;
  int row0 = n_base + bx*128;
  int coltile = by*128;

  f4_t acc[4][4];
  #pragma unroll
  for (int i=0;i<4;i++)
    #pragma unroll
    for (int j=0;j<4;j++) acc[i][j] = (f4_t){0.f,0.f,0.f,0.f};

  int srr = t>>3;                 // staging: row within a 32-row group = it*32 + srr
  int sck = t&7;                  // staging: 16B chunk within the 128B row
  int arow = (w&1)*64 + m16;      // fragment A row base (within tile)
  int brow = (w>>1)*64 + m16;     // fragment B col-row base
  int swz  = m16 & 7;             // read-side chunk swizzle

  auto STAGE = [&](int kk, int buf){
    int seg = kk>>2;
    int kloc = (kk&3)*64;
    #pragma unroll
    for (int it=0; it<4; ++it){
      int drow = it*32 + srr;                 // dest row 0..127
      int sc = (sck ^ (drow&7)) << 3;         // swizzled source col offset (elems)
      int r = row0 + drow;
      const __bf16* asrc;
      if (seg==0)      asrc = xe + (size_t)r*Hz + kloc + sc;
      else if (seg==3) asrc = h + (size_t)r*Hz + kloc + sc;
      else if (seg==1) asrc = ((r&1023)==0)    ? zbuf : h + ((size_t)(r-1)*Hz + kloc + sc);
      else             asrc = ((r&1023)==1023) ? zbuf : h + ((size_t)(r+1)*Hz + kloc + sc);
      gl_lds16(asrc, &sA[buf][drow*64 + sck*8]);
      const __bf16* bsrc = Wt + (size_t)(coltile + drow)*1024 + seg*256 + kloc + sc;
      gl_lds16(bsrc, &sB[buf][drow*64 + sck*8]);
    }
  };

  int kk_s = (by >= 12) ? 12 : 0;              // gate-6 cols: only seg 3
  STAGE(kk_s, 0);
  __syncthreads();                             // drains vmcnt(0): buf0 ready
  int cur = 0;
  #pragma unroll 1
  for (int kk=kk_s; kk<16; ++kk){
    if (kk < 15) STAGE(kk+1, cur^1);           // prefetch next K-step
    const char* Ab = (const char*)sA[cur];
    const char* Bb = (const char*)sB[cur];
    #pragma unroll
    for (int kb=0; kb<2; ++kb){
      bf8_t a[4], bb[4];
      int cofs = ((kb*4 + p) ^ swz) << 4;     // swizzled 16B chunk
      #pragma unroll
      for (int tr=0;tr<4;tr++)
        a[tr] = *(const bf8_t*)(Ab + (arow + tr*16)*128 + cofs);
      #pragma unroll
      for (int tc=0;tc<4;tc++)
        bb[tc] = *(const bf8_t*)(Bb + (brow + tc*16)*128 + cofs);
      #pragma unroll
      for (int tr=0;tr<4;tr++)
        #pragma unroll
        for (int tc=0;tc<4;tc++)
          acc[tr][tc] = __builtin_amdgcn_mfma_f32_16x16x32_bf16(a[tr], bb[tc], acc[tr][tc], 0, 0, 0);
    }
    __syncthreads();                           // next buf staged + cur free for overwrite
    cur ^= 1;
  }

  int trg0 = (bx*128 + (w&1)*64) >> 4;         // chunk-local tile row
  int tcg0 = (coltile + (w>>1)*64) >> 4;
  #pragma unroll
  for (int tr=0;tr<4;tr++){
    #pragma unroll
    for (int tc=0;tc<4;tc++){
      size_t tile = (size_t)(trg0+tr)*NTC + (tcg0+tc);
      bf4_t o;
      o[0]=(__bf16)acc[tr][tc][0]; o[1]=(__bf16)acc[tr][tc][1];
      o[2]=(__bf16)acc[tr][tc][2]; o[3]=(__bf16)acc[tr][tc][3];
      *(bf4_t*)(pre + tile*256 + lane*4) = o;
    }
  }
}

// ---- epilogue (1024 threads): wave w16 owns cols [w16*16, w16*16+16) across all 7 gates ----
// v6 = round-4 best (DPP stage-1 reduce + 112-thread stage-2) + XCD swizzle so each
// epi block lands on the XCD whose gemm blocks wrote its `pre` rows (L2 hits).
__global__ __launch_bounds__(1024) void k_epi(
    const __bf16* __restrict__ pre, const __bf16* __restrict__ xe,
    const __bf16* __restrict__ cc, const float* __restrict__ mask,
    const float* __restrict__ dhWd7, const float* __restrict__ b_g,
    const float* __restrict__ gb3, const float* __restrict__ ln_a, const float* __restrict__ ln_b,
    const float* __restrict__ dc,
    float* __restrict__ outf, __bf16* __restrict__ hn, __bf16* __restrict__ cn,
    float* __restrict__ pm, float* __restrict__ ps, float* __restrict__ pn,
    int n_base, int last){
  __shared__ float sred_s[16][7][16];   // [wave][gate][row]
  __shared__ float sred_q[16][7][16];
  __shared__ float smean[7][16];
  __shared__ float sisd[7][16];
  __shared__ float hsh[16*260];
  int t = threadIdx.x;
  // XCD swizzle: hw block f -> row chunk be, matching gemm's bx->XCD grouping:
  // gemm bx group [16r,16r+16) on XCD r covers rows [2048r, 2048(r+1)) = be in [128r,128r+128).
  int f = blockIdx.x;                    // 0..1023
  int be = (f&7)*128 + (f>>3);           // bijective (1024 = 8*128)
  int n0 = n_base + be*16;
  int b = n0 >> 10;
  int w16 = t>>6, lane = t&63, m16 = lane&15, p = lane>>4;
  int col = w16*16 + m16;
  size_t trk = be;

  // ---- hoisted loads: all global reads issued before any dependent compute ----
  bf4_t pv[7];
  float wd[7], bg[7], la[7], lb[7];
  #pragma unroll
  for (int g=0; g<7; ++g){
    size_t tile = trk*NTC + g*16 + w16;
    pv[g] = *(const bf4_t*)(pre + tile*256 + lane*4);
    wd[g] = dhWd7[(g*Bz + b)*Hz + col];
    bg[g] = (g<6) ? b_g[g*Hz + col] : gb3[col];
    int lnr = (g<6) ? g : 8;
    la[g] = ln_a[lnr*Hz+col]; lb[g] = ln_b[lnr*Hz+col];
  }
  float msk4[4], cvv[4], cb4[4], ca4[4], em4[4];
  #pragma unroll
  for (int reg=0; reg<4; ++reg){
    int n2 = n0 + p*4 + reg;
    int l2 = n2 & 1023;
    msk4[reg] = mask[n2];
    cvv[reg] = (float)cc[(size_t)n2*Hz + col];
    cb4[reg] = (l2==0)    ? 0.f : (float)cc[(size_t)(n2-1)*Hz + col];
    ca4[reg] = (l2==1023) ? 0.f : (float)cc[(size_t)(n2+1)*Hz + col];
    em4[reg] = (float)xe[(size_t)n2*Hz + col];
  }
  float tdc = dc[b*Hz + col];

  // ---- LN stage 1: 16-lane reduce per gate via DPP (VALU pipe, no DS ops) ----
  float acc[7][4];
  #pragma unroll
  for (int g=0; g<7; ++g){
    float s_r[4], q_r[4];
    #pragma unroll
    for (int reg=0; reg<4; ++reg){
      float x = (float)pv[g][reg] + msk4[reg]*wd[g] + bg[g];
      acc[g][reg] = x;
      s_r[reg] = dppsum16(x);
      q_r[reg] = dppsum16(x*x);
    }
    if (m16==15){
      #pragma unroll
      for (int reg=0; reg<4; ++reg){
        sred_s[w16][g][p*4+reg] = s_r[reg];
        sred_q[w16][g][p*4+reg] = q_r[reg];
      }
    }
  }
  __syncthreads();

  // ---- LN stage 2: 112 threads, one per (gate,row), sum across 16 waves ----
  if (t < 112){
    int g = t>>4, row = t&15;
    float ss=0.f, qq=0.f;
    #pragma unroll
    for (int ww=0; ww<16; ++ww){
      ss += sred_s[ww][g][row];
      qq += sred_q[ww][g][row];
    }
    float mean = ss*(1.f/Hz);
    float var  = (qq - (float)Hz*mean*mean)*(1.f/(Hz-1));
    smean[g][row] = mean;
    sisd[g][row]  = __builtin_amdgcn_rcpf(sqrtf(fmaxf(var,0.f))+EPSz);
  }
  __syncthreads();

  // ---- normalize + sigmoid (fully unrolled: acc statically indexed) ----
  #pragma unroll
  for (int g=0; g<7; ++g){
    #pragma unroll
    for (int reg=0; reg<4; ++reg){
      int row = p*4+reg;
      acc[g][reg] = fsig(la[g]*(acc[g][reg]-smean[g][row])*sisd[g][row] + lb[g]);
    }
  }

  // gate-6: msm + online-softmax partials over the block's 16 rows per column
  {
    float mm = -1e30f, gfv[4];
    #pragma unroll
    for (int reg=0; reg<4; ++reg){
      float gv = acc[6][reg] + (msk4[reg]*1e25f - 1e25f);
      gfv[reg] = gv;
      mm = fmaxf(mm, gv);
    }
    float ss=0.f, nn=0.f;
    #pragma unroll
    for (int reg=0; reg<4; ++reg){
      float e = __expf(gfv[reg]-mm);
      ss += e; nn += e*cvv[reg];
    }
    #pragma unroll
    for (int off=16; off<64; off<<=1){
      float mo = __shfl_xor(mm, off, 64);
      float so = __shfl_xor(ss, off, 64);
      float no = __shfl_xor(nn, off, 64);
      float mN = fmaxf(mm, mo);
      float ea = __expf(mm-mN), eb = __expf(mo-mN);
      ss = ss*ea + so*eb; nn = nn*ea + no*eb; mm = mN;
    }
    if (p==0){
      int ch = (n0 >> 4) & (NCH-1);
      int idx = (b*NCH + ch)*Hz + col;
      pm[idx]=mm; ps[idx]=ss; pn[idx]=nn;
    }
  }

  // 5-softmax + cell update
  float cnv[4];
  #pragma unroll
  for (int reg=0; reg<4; ++reg){
    float msk = msk4[reg];
    float g0=acc[0][reg], g1=acc[1][reg], g2=acc[2][reg], g3=acc[3][reg], g4=acc[4][reg];
    float m5 = fmaxf(fmaxf(fmaxf(g0,g1),fmaxf(g2,g3)),g4);
    float e0=__expf(g0-m5), e1=__expf(g1-m5), e2=__expf(g2-m5), e3=__expf(g3-m5), e4=__expf(g4-m5);
    float inv = __builtin_amdgcn_rcpf(e0+e1+e2+e3+e4);
    float cnew = (cb4[reg]*e0 + ca4[reg]*e1 + em4[reg]*e2 + (tdc*msk)*e3 + cvv[reg]*e4)*inv;
    float hv = acc[5][reg]*ftanh(cnew);
    hsh[(p*4+reg)*260 + col] = hv*msk;
    cnv[reg] = cnew*msk;
  }
  __syncthreads();
  {
    int row = t>>6, c4 = lane*4;
    int n = n0 + row;
    const float* src = hsh + row*260 + c4;
    float v0=src[0], v1=src[1], v2=src[2], v3=src[3];
    if (last){
      *(float4*)(outf + (size_t)n*Hz + c4) = make_float4(v0,v1,v2,v3);
    } else {
      bf4_t o; o[0]=(__bf16)v0; o[1]=(__bf16)v1; o[2]=(__bf16)v2; o[3]=(__bf16)v3;
      *(bf4_t*)(hn + (size_t)n*Hz + c4) = o;
    }
  }
  __syncthreads();
  #pragma unroll
  for (int reg=0; reg<4; ++reg) hsh[(p*4+reg)*260 + col] = cnv[reg];
  __syncthreads();
  {
    int row = t>>6, c4 = lane*4;
    const float* src = hsh + row*260 + c4;
    bf4_t o; o[0]=(__bf16)src[0]; o[1]=(__bf16)src[1]; o[2]=(__bf16)src[2]; o[3]=(__bf16)src[3];
    *(bf4_t*)(cn + (size_t)(n0+row)*Hz + c4) = o;
  }
}

// ---- combine partials + gd/gi slots -> dc_new, dh_new ----
__global__ void k_soft_comb(const float* __restrict__ pm, const float* __restrict__ ps,
    const float* __restrict__ pn,
    const float* __restrict__ gd, const float* __restrict__ gi, const float* __restrict__ go,
    const float* __restrict__ tgg, const float* __restrict__ dc,
    float* __restrict__ dc_new, float* __restrict__ dh_new){
  int b = blockIdx.x, t = threadIdx.x;
  float vgd = gd[b*Hz+t], vgi = gi[b*Hz+t];
  float m = fmaxf(vgd, vgi);
  for (int ch=0; ch<NCH; ch++) m = fmaxf(m, pm[(b*NCH+ch)*Hz + t]);
  float ed = expf(vgd - m), ei = expf(vgi - m);
  float s  = ed + ei;
  float num = ed*dc[b*Hz+t] + ei*tgg[b*Hz+t];
  for (int ch=0; ch<NCH; ch++){
    int idx = (b*NCH+ch)*Hz + t;
    float e = expf(pm[idx] - m);
    s   += ps[idx]*e;
    num += pn[idx]*e;
  }
  float dcn = num/s;
  dc_new[b*Hz+t] = dcn;
  dh_new[b*Hz+t] = go[b*Hz+t]*tanhf(dcn);
}

extern "C" void kernel_launch(void* const* d_in, const int* in_sizes, int n_in,
                              void* d_out, int out_size, void* d_ws, size_t ws_size,
                              hipStream_t stream) {
  const float* word  = (const float*)d_in[0];
  const float* sent  = (const float*)d_in[1];
  const float* mask  = (const float*)d_in[2];
  const float* h0    = (const float*)d_in[3];
  const float* c0    = (const float*)d_in[4];
  const float* Wx_g  = (const float*)d_in[5];
  const float* Wh_g  = (const float*)d_in[6];
  const float* Wi_g  = (const float*)d_in[7];
  const float* Wd_g  = (const float*)d_in[8];
  const float* b_g   = (const float*)d_in[9];
  const float* gWx   = (const float*)d_in[10];
  const float* gWh   = (const float*)d_in[11];
  const float* gWg   = (const float*)d_in[12];
  const float* gb    = (const float*)d_in[13];
  const float* ln_a  = (const float*)d_in[14];
  const float* ln_b  = (const float*)d_in[15];
  float* out = (float*)d_out;

  char* wc = (char*)d_ws;
  __bf16* xe  = (__bf16*)wc;  wc += NHz*2;                         // 16.8 MB
  __bf16* h_a = (__bf16*)wc;  wc += NHz*2;                         // 16.8 MB
  __bf16* h_b = (__bf16*)wc;  wc += NHz*2;                         // 16.8 MB
  __bf16* c_a = (__bf16*)wc;  wc += NHz*2;                         // 16.8 MB
  __bf16* c_b = (__bf16*)wc;  wc += NHz*2;                         // 16.8 MB
  __bf16* pre = (__bf16*)wc;  wc += (size_t)(CHR/16)*NTC*256*2;    // 58.7 MB
  __bf16* Wt  = (__bf16*)wc;  wc += (size_t)1792*1024*2;           // 3.7 MB
  __bf16* zbuf = (__bf16*)wc; wc += 256;                           // 256 B zero page
  float* dh_a = (float*)wc;   wc += BHz*4;
  float* dh_b = (float*)wc;   wc += BHz*4;
  float* dc_a = (float*)wc;   wc += BHz*4;
  float* dc_b = (float*)wc;   wc += BHz*4;
  float* comb = (float*)wc;   wc += BHz*4;
  float* gd   = (float*)wc;   wc += BHz*4;
  float* gi_  = (float*)wc;   wc += BHz*4;
  float* go_  = (float*)wc;   wc += BHz*4;
  float* tgg  = (float*)wc;   wc += BHz*4;
  float* dhWd7 = (float*)wc;  wc += 7*BHz*4;
  float* pmean = (float*)wc;  wc += 8*BHz*4;
  float* pm = (float*)wc;     wc += (size_t)Bz*NCH*Hz*4;
  float* ps = (float*)wc;     wc += (size_t)Bz*NCH*Hz*4;
  float* pn = (float*)wc;     wc += (size_t)Bz*NCH*Hz*4;
  // total ~153 MB  (keep well under the ~208 MB proven-safe bound)

  // setup
  k_packWt<<<896, 256, 0, stream>>>(Wx_g, Wh_g, Wi_g, gWh + 3*Hz*Hz, Wt, zbuf);
  k_initb<<<4096, 256, 0, stream>>>(word, h0, c0, mask, xe, h_a, c_a);
  k_meanpb<<<dim3(Bz,8), 256, 0, stream>>>(h_a, pmean);
  k_comb8<<<Bz, 256, 0, stream>>>(pmean, dh_a);
  k_meanpb<<<dim3(Bz,8), 256, 0, stream>>>(c_a, pmean);
  k_comb8<<<Bz, 256, 0, stream>>>(pmean, dc_a);

  __bf16* hc=h_a; __bf16* hn=h_b;
  __bf16* cc=c_a; __bf16* cn=c_b;
  float* dhc=dh_a; float* dcc=dc_a; float* dhn=dh_b; float* dcn=dc_b;

  for (int layer=0; layer<NLAYERS; ++layer){
    k_meanpb<<<dim3(Bz,8), 256, 0, stream>>>(hc, pmean);
    k_comb8<<<Bz, 256, 0, stream>>>(pmean, comb);
    k_small<<<dim3(Bz,11), 256, 0, stream>>>(dhc, comb, sent, gWx, gWh, gWg, gb, Wd_g,
                                             ln_a, ln_b, gd, gi_, go_, tgg, dhWd7);
    int last = (layer == NLAYERS-1) ? 1 : 0;
    for (int chunk=0; chunk<Nz/CHR; ++chunk){
      int n_base = chunk*CHR;
      k_gemm<<<dim3(CHR/128, 14), 256, 0, stream>>>(xe, hc, Wt, zbuf, pre, n_base);
      k_epi<<<CHR/16, 1024, 0, stream>>>(pre, xe, cc, mask, dhWd7, b_g, gb + 3*Hz,
                                         ln_a, ln_b, dcc, out, hn, cn, pm, ps, pn,
                                         n_base, last);
    }
    k_soft_comb<<<Bz, 256, 0, stream>>>(pm, ps, pn, gd, gi_, go_, tgg, dcc, dcn, dhn);
    __bf16* tb;
    tb=hc; hc=hn; hn=tb;
    tb=cc; cc=cn; cn=tb;
    float* tmp;
    tmp=dhc; dhc=dhn; dhn=tmp;
    tmp=dcc; dcc=dcn; dcn=tmp;
  }
  (void)in_sizes; (void)n_in; (void)out_size; (void)ws_size;
}

// Round 12
// 1381.842 us; speedup vs baseline: 1.0490x; 1.0490x over previous
//
#include <hip/hip_runtime.h>
#include <cstddef>

#define Bz 32
#define Lz 1024
#define Hz 256
#define Nz (Bz*Lz)          // 32768
#define NHz ((size_t)Nz*Hz) // 8388608
#define BHz (Bz*Hz)         // 8192
#define EPSz 1e-3f
#define NLAYERS 4
#define NCH 64              // 16-row softmax chunks per batch
#define NTC 112             // tile-cols in pre (7 gates * 16)
#define CHR 16384           // rows per GEMM/epi chunk

typedef __bf16 bf8_t __attribute__((ext_vector_type(8)));
typedef __bf16 bf4_t __attribute__((ext_vector_type(4)));
typedef float  f4_t  __attribute__((ext_vector_type(4)));

__device__ inline float sigmoidf(float x){ return 1.f/(1.f+expf(-x)); }
// fast versions (v_exp_f32 / v_rcp_f32): rel err ~1e-7, invisible under bf16 rounding
__device__ inline float fsig(float x){ return __builtin_amdgcn_rcpf(1.f + __expf(-x)); }
__device__ inline float ftanh(float x){ return 1.f - 2.f*__builtin_amdgcn_rcpf(__expf(2.f*x)+1.f); }

// DPP row_shr add: reduce over the 16-lane DPP row on the VALU pipe (not DS).
// After shr 1,2,4,8 lane (lane&15)==15 holds the 16-lane row sum.
template<int C>
__device__ inline float dppadd(float v){
  int t = __builtin_amdgcn_update_dpp(0, __builtin_bit_cast(int, v), C, 0xf, 0xf, true);
  return v + __builtin_bit_cast(float, t);
}
__device__ inline float dppsum16(float v){
  v = dppadd<0x111>(v);   // row_shr:1
  v = dppadd<0x112>(v);   // row_shr:2
  v = dppadd<0x114>(v);   // row_shr:4
  v = dppadd<0x118>(v);   // row_shr:8
  return v;
}

// async global->LDS, 16B per lane.  LDS dest must be uniform-base + lane*16.
__device__ inline void gl_lds16(const void* g, void* l){
  __builtin_amdgcn_global_load_lds(
      (const __attribute__((address_space(1))) void*)g,
      (__attribute__((address_space(3))) void*)l, 16, 0, 0);
}

__device__ inline float2 block_sum2(float a, float b, float* red){
  #pragma unroll
  for (int off=32; off; off>>=1){ a += __shfl_down(a,off,64); b += __shfl_down(b,off,64); }
  int w = threadIdx.x>>6;
  __syncthreads();
  if ((threadIdx.x&63)==0){ red[w]=a; red[4+w]=b; }
  __syncthreads();
  return make_float2(red[0]+red[1]+red[2]+red[3], red[4]+red[5]+red[6]+red[7]);
}

__device__ inline float ln_block(float v, const float* la, const float* lb, int t, float* red){
  float2 ss = block_sum2(v, v*v, red);
  float mean = ss.x*(1.f/Hz);
  float var  = (ss.y - (float)Hz*mean*mean)*(1.f/(Hz-1));
  float isd  = 1.f/(sqrtf(fmaxf(var,0.f))+EPSz);
  return la[t]*(v-mean)*isd + lb[t];
}

// ---- init: xe = word*mask, h = h0*mask, c = c0*mask (all bf16) ----
__global__ void k_initb(const float* __restrict__ word, const float* __restrict__ h0,
                        const float* __restrict__ c0, const float* __restrict__ mask,
                        __bf16* __restrict__ xe, __bf16* __restrict__ h, __bf16* __restrict__ c){
  int tid = blockIdx.x*256 + threadIdx.x;      // Nz*32 threads
  int n = tid >> 5; int c8 = (tid & 31)*8;
  float m = mask[n];
  size_t off = (size_t)n*Hz + c8;
  const float4* wv = (const float4*)(word + off);
  float4 w0 = wv[0], w1 = wv[1];
  bf8_t o;
  o[0]=(__bf16)(w0.x*m); o[1]=(__bf16)(w0.y*m); o[2]=(__bf16)(w0.z*m); o[3]=(__bf16)(w0.w*m);
  o[4]=(__bf16)(w1.x*m); o[5]=(__bf16)(w1.y*m); o[6]=(__bf16)(w1.z*m); o[7]=(__bf16)(w1.w*m);
  *(bf8_t*)(xe + off) = o;
  const float4* hv = (const float4*)(h0 + off);
  float4 a0 = hv[0], a1 = hv[1];
  o[0]=(__bf16)(a0.x*m); o[1]=(__bf16)(a0.y*m); o[2]=(__bf16)(a0.z*m); o[3]=(__bf16)(a0.w*m);
  o[4]=(__bf16)(a1.x*m); o[5]=(__bf16)(a1.y*m); o[6]=(__bf16)(a1.z*m); o[7]=(__bf16)(a1.w*m);
  *(bf8_t*)(h + off) = o;
  const float4* cv = (const float4*)(c0 + off);
  float4 b0 = cv[0], b1 = cv[1];
  o[0]=(__bf16)(b0.x*m); o[1]=(__bf16)(b0.y*m); o[2]=(__bf16)(b0.z*m); o[3]=(__bf16)(b0.w*m);
  o[4]=(__bf16)(b1.x*m); o[5]=(__bf16)(b1.y*m); o[6]=(__bf16)(b1.z*m); o[7]=(__bf16)(b1.w*m);
  *(bf8_t*)(c + off) = o;
}

// ---- pack 7-gate weights into Wt[col][k] row-major (1792 x 1024, bf16) ----
__global__ void k_packWt(const float* __restrict__ Wx, const float* __restrict__ Wh,
                         const float* __restrict__ Wi, const float* __restrict__ gWh3,
                         __bf16* __restrict__ Wt, __bf16* __restrict__ zbuf){
  int tid = blockIdx.x*256 + threadIdx.x;   // 896*256 = 1792*128
  if (tid < 128) zbuf[tid] = (__bf16)0.f;
  int col = tid >> 7;
  int k0  = (tid & 127) << 3;
  if (col >= 1792) return;
  int g = col >> 8, cg = col & 255;
  int seg = k0 >> 8, kl0 = k0 & 255;        // 8 consecutive k stay in one seg
  bf8_t o;
  #pragma unroll
  for (int j=0;j<8;j++){
    int kl = kl0 + j;
    float v = 0.f;
    if (g < 6){
      if (seg==0)      v = Wx[((size_t)g*256 + kl)*256 + cg];
      else if (seg==1) v = Wh[((size_t)g*512 + kl)*256 + cg];
      else if (seg==2) v = Wh[((size_t)g*512 + 256 + kl)*256 + cg];
      else             v = Wi[((size_t)g*256 + kl)*256 + cg];
    } else {
      if (seg==3)      v = gWh3[(size_t)kl*256 + cg];
    }
    o[j] = (__bf16)v;
  }
  *(bf8_t*)(Wt + (size_t)col*1024 + k0) = o;
}

// ---- mean over L of a bf16 tensor, two-stage ----
__global__ void k_meanpb(const __bf16* __restrict__ x, float* __restrict__ part){
  int b = blockIdx.x, ch = blockIdx.y, t = threadIdx.x;
  const __bf16* p = x + ((size_t)b*Lz + ch*128)*Hz + t;
  float s = 0.f;
  #pragma unroll 4
  for (int l=0;l<128;l++) s += (float)p[(size_t)l*Hz];
  part[(b*8+ch)*Hz + t] = s;
}
__global__ void k_comb8(const float* __restrict__ part, float* __restrict__ o){
  int b = blockIdx.x, t = threadIdx.x;
  float s = 0.f;
  #pragma unroll
  for (int ch=0;ch<8;ch++) s += part[(b*8+ch)*Hz + t];
  o[b*Hz+t] = s*(1.f/Lz);
}

// ---- sentence-level gates + broadcast matvecs.  grid (B, 11) ----
__global__ __launch_bounds__(256) void k_small(
    const float* __restrict__ dh, const float* __restrict__ comb, const float* __restrict__ sent,
    const float* __restrict__ gWx, const float* __restrict__ gWh, const float* __restrict__ gWg,
    const float* __restrict__ gb, const float* __restrict__ Wd_g,
    const float* __restrict__ ln_a, const float* __restrict__ ln_b,
    float* __restrict__ gd, float* __restrict__ gi, float* __restrict__ go,
    float* __restrict__ tgg, float* __restrict__ dhWd7){
  int b = blockIdx.x, which = blockIdx.y, t = threadIdx.x;
  __shared__ float sdh[Hz], sse[Hz], sco[Hz];
  __shared__ float red[8];
  sdh[t]=dh[b*Hz+t]; sse[t]=sent[b*Hz+t]; sco[t]=comb[b*Hz+t];
  __syncthreads();
  float acc=0.f;
  if (which < 3){
    const float* W0 = gWx + which*Hz*Hz;
    const float* W1 = gWg + which*Hz*Hz;
    const float* W2 = gWh + which*Hz*Hz;
    for (int k=0;k<Hz;k++) acc += sdh[k]*W0[k*Hz+t] + sse[k]*W1[k*Hz+t] + sco[k]*W2[k*Hz+t];
    if (which==0){
      float r = ln_block(acc + gb[0*Hz+t], ln_a+6*Hz, ln_b+6*Hz, t, red);
      gd[b*Hz+t] = sigmoidf(r);
    } else if (which==1){
      float r = ln_block(acc, ln_a+9*Hz, ln_b+9*Hz, t, red);
      gi[b*Hz+t] = sigmoidf(r + gb[1*Hz+t]);
    } else {
      float r = ln_block(acc + gb[2*Hz+t], ln_a+7*Hz, ln_b+7*Hz, t, red);
      go[b*Hz+t] = sigmoidf(r);
    }
  } else if (which == 3){
    const float* W = gWg + 3*Hz*Hz;
    for (int k=0;k<Hz;k++) acc += sse[k]*W[k*Hz+t];
    float r = ln_block(acc, ln_a+10*Hz, ln_b+10*Hz, t, red);
    tgg[b*Hz+t] = tanhf(r);
  } else if (which == 4){
    const float* W = gWx + 3*Hz*Hz;          // dh @ gWx[3] -> slot 6
    for (int k=0;k<Hz;k++) acc += sdh[k]*W[k*Hz+t];
    dhWd7[(6*Bz + b)*Hz + t] = acc;
  } else {
    int g = which-5;
    const float* W = Wd_g + g*Hz*Hz;
    for (int k=0;k<Hz;k++) acc += sdh[k]*W[k*Hz+t];
    dhWd7[(g*Bz + b)*Hz + t] = acc;
  }
}

// ---- GEMM: [xe | h(n-1) | h(n+1) | h(n)](rows x 1024) @ Wt^T(1024 x 1792) -> pre ----
// Round-4 best config: 128x128 tile, 4 waves, BK=64, double-buffered LDS
// (T3-minimum 2-phase): STAGE(k+1) issued before compute(k), one barrier per
// K-step.  Default block order (bx fast) keeps Wt-panel reuse in L2 — measured
// faster than any XCD remap (round-11: swizzle +35% FETCH, +8 us).
__global__ __launch_bounds__(256) void k_gemm(
    const __bf16* __restrict__ xe, const __bf16* __restrict__ h,
    const __bf16* __restrict__ Wt, const __bf16* __restrict__ zbuf,
    __bf16* __restrict__ pre, int n_base){
  __shared__ __align__(16) __bf16 sA[2][128*64];   // [row][64] row-major, chunk-swizzled
  __shared__ __align__(16) __bf16 sB[2][128*64];   // [col][64] row-major, chunk-swizzled
  int t = threadIdx.x;
  int w = t>>6, lane = t&63;
  int m16 = lane&15, p = lane>>4;
  int bx = blockIdx.x, by = blockIdx.y;
  int row0 = n_base + bx*128;
  int coltile = by*128;

  f4_t acc[4][4];
  #pragma unroll
  for (int i=0;i<4;i++)
    #pragma unroll
    for (int j=0;j<4;j++) acc[i][j] = (f4_t){0.f,0.f,0.f,0.f};

  int srr = t>>3;                 // staging: row within a 32-row group = it*32 + srr
  int sck = t&7;                  // staging: 16B chunk within the 128B row
  int arow = (w&1)*64 + m16;      // fragment A row base (within tile)
  int brow = (w>>1)*64 + m16;     // fragment B col-row base
  int swz  = m16 & 7;             // read-side chunk swizzle

  auto STAGE = [&](int kk, int buf){
    int seg = kk>>2;
    int kloc = (kk&3)*64;
    #pragma unroll
    for (int it=0; it<4; ++it){
      int drow = it*32 + srr;                 // dest row 0..127
      int sc = (sck ^ (drow&7)) << 3;         // swizzled source col offset (elems)
      int r = row0 + drow;
      const __bf16* asrc;
      if (seg==0)      asrc = xe + (size_t)r*Hz + kloc + sc;
      else if (seg==3) asrc = h + (size_t)r*Hz + kloc + sc;
      else if (seg==1) asrc = ((r&1023)==0)    ? zbuf : h + ((size_t)(r-1)*Hz + kloc + sc);
      else             asrc = ((r&1023)==1023) ? zbuf : h + ((size_t)(r+1)*Hz + kloc + sc);
      gl_lds16(asrc, &sA[buf][drow*64 + sck*8]);
      const __bf16* bsrc = Wt + (size_t)(coltile + drow)*1024 + seg*256 + kloc + sc;
      gl_lds16(bsrc, &sB[buf][drow*64 + sck*8]);
    }
  };

  int kk_s = (by >= 12) ? 12 : 0;              // gate-6 cols: only seg 3
  STAGE(kk_s, 0);
  __syncthreads();                             // drains vmcnt(0): buf0 ready
  int cur = 0;
  #pragma unroll 1
  for (int kk=kk_s; kk<16; ++kk){
    if (kk < 15) STAGE(kk+1, cur^1);           // prefetch next K-step
    const char* Ab = (const char*)sA[cur];
    const char* Bb = (const char*)sB[cur];
    #pragma unroll
    for (int kb=0; kb<2; ++kb){
      bf8_t a[4], bb[4];
      int cofs = ((kb*4 + p) ^ swz) << 4;     // swizzled 16B chunk
      #pragma unroll
      for (int tr=0;tr<4;tr++)
        a[tr] = *(const bf8_t*)(Ab + (arow + tr*16)*128 + cofs);
      #pragma unroll
      for (int tc=0;tc<4;tc++)
        bb[tc] = *(const bf8_t*)(Bb + (brow + tc*16)*128 + cofs);
      #pragma unroll
      for (int tr=0;tr<4;tr++)
        #pragma unroll
        for (int tc=0;tc<4;tc++)
          acc[tr][tc] = __builtin_amdgcn_mfma_f32_16x16x32_bf16(a[tr], bb[tc], acc[tr][tc], 0, 0, 0);
    }
    __syncthreads();                           // next buf staged + cur free for overwrite
    cur ^= 1;
  }

  int trg0 = (bx*128 + (w&1)*64) >> 4;         // chunk-local tile row
  int tcg0 = (coltile + (w>>1)*64) >> 4;
  #pragma unroll
  for (int tr=0;tr<4;tr++){
    #pragma unroll
    for (int tc=0;tc<4;tc++){
      size_t tile = (size_t)(trg0+tr)*NTC + (tcg0+tc);
      bf4_t o;
      o[0]=(__bf16)acc[tr][tc][0]; o[1]=(__bf16)acc[tr][tc][1];
      o[2]=(__bf16)acc[tr][tc][2]; o[3]=(__bf16)acc[tr][tc][3];
      *(bf4_t*)(pre + tile*256 + lane*4) = o;
    }
  }
}

// ---- epilogue (1024 threads): wave w16 owns cols [w16*16, w16*16+16) across all 7 gates ----
// Round-4 best: stage-1 LN reduce via DPP row_shr on the VALU pipe (no DS ops),
// writer lane m16==15; 112-thread stage-2; full static unroll; fast exp/rcp.
__global__ __launch_bounds__(1024) void k_epi(
    const __bf16* __restrict__ pre, const __bf16* __restrict__ xe,
    const __bf16* __restrict__ cc, const float* __restrict__ mask,
    const float* __restrict__ dhWd7, const float* __restrict__ b_g,
    const float* __restrict__ gb3, const float* __restrict__ ln_a, const float* __restrict__ ln_b,
    const float* __restrict__ dc,
    float* __restrict__ outf, __bf16* __restrict__ hn, __bf16* __restrict__ cn,
    float* __restrict__ pm, float* __restrict__ ps, float* __restrict__ pn,
    int n_base, int last){
  __shared__ float sred_s[16][7][16];   // [wave][gate][row]
  __shared__ float sred_q[16][7][16];
  __shared__ float smean[7][16];
  __shared__ float sisd[7][16];
  __shared__ float hsh[16*260];
  int t = threadIdx.x;
  int n0 = n_base + blockIdx.x*16;
  int b = n0 >> 10;
  int w16 = t>>6, lane = t&63, m16 = lane&15, p = lane>>4;
  int col = w16*16 + m16;
  size_t trk = blockIdx.x;

  // ---- hoisted loads: all global reads issued before any dependent compute ----
  bf4_t pv[7];
  float wd[7], bg[7], la[7], lb[7];
  #pragma unroll
  for (int g=0; g<7; ++g){
    size_t tile = trk*NTC + g*16 + w16;
    pv[g] = *(const bf4_t*)(pre + tile*256 + lane*4);
    wd[g] = dhWd7[(g*Bz + b)*Hz + col];
    bg[g] = (g<6) ? b_g[g*Hz + col] : gb3[col];
    int lnr = (g<6) ? g : 8;
    la[g] = ln_a[lnr*Hz+col]; lb[g] = ln_b[lnr*Hz+col];
  }
  float msk4[4], cvv[4], cb4[4], ca4[4], em4[4];
  #pragma unroll
  for (int reg=0; reg<4; ++reg){
    int n2 = n0 + p*4 + reg;
    int l2 = n2 & 1023;
    msk4[reg] = mask[n2];
    cvv[reg] = (float)cc[(size_t)n2*Hz + col];
    cb4[reg] = (l2==0)    ? 0.f : (float)cc[(size_t)(n2-1)*Hz + col];
    ca4[reg] = (l2==1023) ? 0.f : (float)cc[(size_t)(n2+1)*Hz + col];
    em4[reg] = (float)xe[(size_t)n2*Hz + col];
  }
  float tdc = dc[b*Hz + col];

  // ---- LN stage 1: 16-lane reduce per gate via DPP (VALU pipe, no DS ops) ----
  float acc[7][4];
  #pragma unroll
  for (int g=0; g<7; ++g){
    float s_r[4], q_r[4];
    #pragma unroll
    for (int reg=0; reg<4; ++reg){
      float x = (float)pv[g][reg] + msk4[reg]*wd[g] + bg[g];
      acc[g][reg] = x;
      s_r[reg] = dppsum16(x);
      q_r[reg] = dppsum16(x*x);
    }
    if (m16==15){
      #pragma unroll
      for (int reg=0; reg<4; ++reg){
        sred_s[w16][g][p*4+reg] = s_r[reg];
        sred_q[w16][g][p*4+reg] = q_r[reg];
      }
    }
  }
  __syncthreads();

  // ---- LN stage 2: 112 threads, one per (gate,row), sum across 16 waves ----
  if (t < 112){
    int g = t>>4, row = t&15;
    float ss=0.f, qq=0.f;
    #pragma unroll
    for (int ww=0; ww<16; ++ww){
      ss += sred_s[ww][g][row];
      qq += sred_q[ww][g][row];
    }
    float mean = ss*(1.f/Hz);
    float var  = (qq - (float)Hz*mean*mean)*(1.f/(Hz-1));
    smean[g][row] = mean;
    sisd[g][row]  = __builtin_amdgcn_rcpf(sqrtf(fmaxf(var,0.f))+EPSz);
  }
  __syncthreads();

  // ---- normalize + sigmoid (fully unrolled: acc statically indexed) ----
  #pragma unroll
  for (int g=0; g<7; ++g){
    #pragma unroll
    for (int reg=0; reg<4; ++reg){
      int row = p*4+reg;
      acc[g][reg] = fsig(la[g]*(acc[g][reg]-smean[g][row])*sisd[g][row] + lb[g]);
    }
  }

  // gate-6: msm + online-softmax partials over the block's 16 rows per column
  {
    float mm = -1e30f, gfv[4];
    #pragma unroll
    for (int reg=0; reg<4; ++reg){
      float gv = acc[6][reg] + (msk4[reg]*1e25f - 1e25f);
      gfv[reg] = gv;
      mm = fmaxf(mm, gv);
    }
    float ss=0.f, nn=0.f;
    #pragma unroll
    for (int reg=0; reg<4; ++reg){
      float e = __expf(gfv[reg]-mm);
      ss += e; nn += e*cvv[reg];
    }
    #pragma unroll
    for (int off=16; off<64; off<<=1){
      float mo = __shfl_xor(mm, off, 64);
      float so = __shfl_xor(ss, off, 64);
      float no = __shfl_xor(nn, off, 64);
      float mN = fmaxf(mm, mo);
      float ea = __expf(mm-mN), eb = __expf(mo-mN);
      ss = ss*ea + so*eb; nn = nn*ea + no*eb; mm = mN;
    }
    if (p==0){
      int ch = (n0 >> 4) & (NCH-1);
      int idx = (b*NCH + ch)*Hz + col;
      pm[idx]=mm; ps[idx]=ss; pn[idx]=nn;
    }
  }

  // 5-softmax + cell update
  float cnv[4];
  #pragma unroll
  for (int reg=0; reg<4; ++reg){
    float msk = msk4[reg];
    float g0=acc[0][reg], g1=acc[1][reg], g2=acc[2][reg], g3=acc[3][reg], g4=acc[4][reg];
    float m5 = fmaxf(fmaxf(fmaxf(g0,g1),fmaxf(g2,g3)),g4);
    float e0=__expf(g0-m5), e1=__expf(g1-m5), e2=__expf(g2-m5), e3=__expf(g3-m5), e4=__expf(g4-m5);
    float inv = __builtin_amdgcn_rcpf(e0+e1+e2+e3+e4);
    float cnew = (cb4[reg]*e0 + ca4[reg]*e1 + em4[reg]*e2 + (tdc*msk)*e3 + cvv[reg]*e4)*inv;
    float hv = acc[5][reg]*ftanh(cnew);
    hsh[(p*4+reg)*260 + col] = hv*msk;
    cnv[reg] = cnew*msk;
  }
  __syncthreads();
  {
    int row = t>>6, c4 = lane*4;
    int n = n0 + row;
    const float* src = hsh + row*260 + c4;
    float v0=src[0], v1=src[1], v2=src[2], v3=src[3];
    if (last){
      *(float4*)(outf + (size_t)n*Hz + c4) = make_float4(v0,v1,v2,v3);
    } else {
      bf4_t o; o[0]=(__bf16)v0; o[1]=(__bf16)v1; o[2]=(__bf16)v2; o[3]=(__bf16)v3;
      *(bf4_t*)(hn + (size_t)n*Hz + c4) = o;
    }
  }
  __syncthreads();
  #pragma unroll
  for (int reg=0; reg<4; ++reg) hsh[(p*4+reg)*260 + col] = cnv[reg];
  __syncthreads();
  {
    int row = t>>6, c4 = lane*4;
    const float* src = hsh + row*260 + c4;
    bf4_t o; o[0]=(__bf16)src[0]; o[1]=(__bf16)src[1]; o[2]=(__bf16)src[2]; o[3]=(__bf16)src[3];
    *(bf4_t*)(cn + (size_t)(n0+row)*Hz + c4) = o;
  }
}

// ---- combine partials + gd/gi slots -> dc_new, dh_new ----
__global__ void k_soft_comb(const float* __restrict__ pm, const float* __restrict__ ps,
    const float* __restrict__ pn,
    const float* __restrict__ gd, const float* __restrict__ gi, const float* __restrict__ go,
    const float* __restrict__ tgg, const float* __restrict__ dc,
    float* __restrict__ dc_new, float* __restrict__ dh_new){
  int b = blockIdx.x, t = threadIdx.x;
  float vgd = gd[b*Hz+t], vgi = gi[b*Hz+t];
  float m = fmaxf(vgd, vgi);
  for (int ch=0; ch<NCH; ch++) m = fmaxf(m, pm[(b*NCH+ch)*Hz + t]);
  float ed = expf(vgd - m), ei = expf(vgi - m);
  float s  = ed + ei;
  float num = ed*dc[b*Hz+t] + ei*tgg[b*Hz+t];
  for (int ch=0; ch<NCH; ch++){
    int idx = (b*NCH+ch)*Hz + t;
    float e = expf(pm[idx] - m);
    s   += ps[idx]*e;
    num += pn[idx]*e;
  }
  float dcn = num/s;
  dc_new[b*Hz+t] = dcn;
  dh_new[b*Hz+t] = go[b*Hz+t]*tanhf(dcn);
}

extern "C" void kernel_launch(void* const* d_in, const int* in_sizes, int n_in,
                              void* d_out, int out_size, void* d_ws, size_t ws_size,
                              hipStream_t stream) {
  const float* word  = (const float*)d_in[0];
  const float* sent  = (const float*)d_in[1];
  const float* mask  = (const float*)d_in[2];
  const float* h0    = (const float*)d_in[3];
  const float* c0    = (const float*)d_in[4];
  const float* Wx_g  = (const float*)d_in[5];
  const float* Wh_g  = (const float*)d_in[6];
  const float* Wi_g  = (const float*)d_in[7];
  const float* Wd_g  = (const float*)d_in[8];
  const float* b_g   = (const float*)d_in[9];
  const float* gWx   = (const float*)d_in[10];
  const float* gWh   = (const float*)d_in[11];
  const float* gWg   = (const float*)d_in[12];
  const float* gb    = (const float*)d_in[13];
  const float* ln_a  = (const float*)d_in[14];
  const float* ln_b  = (const float*)d_in[15];
  float* out = (float*)d_out;

  char* wc = (char*)d_ws;
  __bf16* xe  = (__bf16*)wc;  wc += NHz*2;                         // 16.8 MB
  __bf16* h_a = (__bf16*)wc;  wc += NHz*2;                         // 16.8 MB
  __bf16* h_b = (__bf16*)wc;  wc += NHz*2;                         // 16.8 MB
  __bf16* c_a = (__bf16*)wc;  wc += NHz*2;                         // 16.8 MB
  __bf16* c_b = (__bf16*)wc;  wc += NHz*2;                         // 16.8 MB
  __bf16* pre = (__bf16*)wc;  wc += (size_t)(CHR/16)*NTC*256*2;    // 58.7 MB
  __bf16* Wt  = (__bf16*)wc;  wc += (size_t)1792*1024*2;           // 3.7 MB
  __bf16* zbuf = (__bf16*)wc; wc += 256;                           // 256 B zero page
  float* dh_a = (float*)wc;   wc += BHz*4;
  float* dh_b = (float*)wc;   wc += BHz*4;
  float* dc_a = (float*)wc;   wc += BHz*4;
  float* dc_b = (float*)wc;   wc += BHz*4;
  float* comb = (float*)wc;   wc += BHz*4;
  float* gd   = (float*)wc;   wc += BHz*4;
  float* gi_  = (float*)wc;   wc += BHz*4;
  float* go_  = (float*)wc;   wc += BHz*4;
  float* tgg  = (float*)wc;   wc += BHz*4;
  float* dhWd7 = (float*)wc;  wc += 7*BHz*4;
  float* pmean = (float*)wc;  wc += 8*BHz*4;
  float* pm = (float*)wc;     wc += (size_t)Bz*NCH*Hz*4;
  float* ps = (float*)wc;     wc += (size_t)Bz*NCH*Hz*4;
  float* pn = (float*)wc;     wc += (size_t)Bz*NCH*Hz*4;
  // total ~153 MB  (keep well under the ~208 MB proven-safe bound)

  // setup
  k_packWt<<<896, 256, 0, stream>>>(Wx_g, Wh_g, Wi_g, gWh + 3*Hz*Hz, Wt, zbuf);
  k_initb<<<4096, 256, 0, stream>>>(word, h0, c0, mask, xe, h_a, c_a);
  k_meanpb<<<dim3(Bz,8), 256, 0, stream>>>(h_a, pmean);
  k_comb8<<<Bz, 256, 0, stream>>>(pmean, dh_a);
  k_meanpb<<<dim3(Bz,8), 256, 0, stream>>>(c_a, pmean);
  k_comb8<<<Bz, 256, 0, stream>>>(pmean, dc_a);

  __bf16* hc=h_a; __bf16* hn=h_b;
  __bf16* cc=c_a; __bf16* cn=c_b;
  float* dhc=dh_a; float* dcc=dc_a; float* dhn=dh_b; float* dcn=dc_b;

  for (int layer=0; layer<NLAYERS; ++layer){
    k_meanpb<<<dim3(Bz,8), 256, 0, stream>>>(hc, pmean);
    k_comb8<<<Bz, 256, 0, stream>>>(pmean, comb);
    k_small<<<dim3(Bz,11), 256, 0, stream>>>(dhc, comb, sent, gWx, gWh, gWg, gb, Wd_g,
                                             ln_a, ln_b, gd, gi_, go_, tgg, dhWd7);
    int last = (layer == NLAYERS-1) ? 1 : 0;
    for (int chunk=0; chunk<Nz/CHR; ++chunk){
      int n_base = chunk*CHR;
      k_gemm<<<dim3(CHR/128, 14), 256, 0, stream>>>(xe, hc, Wt, zbuf, pre, n_base);
      k_epi<<<CHR/16, 1024, 0, stream>>>(pre, xe, cc, mask, dhWd7, b_g, gb + 3*Hz,
                                         ln_a, ln_b, dcc, out, hn, cn, pm, ps, pn,
                                         n_base, last);
    }
    k_soft_comb<<<Bz, 256, 0, stream>>>(pm, ps, pn, gd, gi_, go_, tgg, dcc, dcn, dhn);
    __bf16* tb;
    tb=hc; hc=hn; hn=tb;
    tb=cc; cc=cn; cn=tb;
    float* tmp;
    tmp=dhc; dhc=dhn; dhn=tmp;
    tmp=dcc; dcc=dcn; dcn=tmp;
  }
  (void)in_sizes; (void)n_in; (void)out_size; (void)ws_size;
}